// Round 1
// baseline (981.755 us; speedup 1.0000x reference)
//
#include <hip/hip_runtime.h>

#define N_NODES 100000
#define N_EDGES 1600000
#define HID 128
#define OUT_CH 64
#define N_GRAPHS 256
#define CHUNK 1024
#define NCHUNK ((N_NODES + CHUNK - 1) / CHUNK)   // 98

// ---------------- init ----------------
__global__ void k_init(int* cnt, float* pooled, float* gcnt) {
  int i = blockIdx.x * blockDim.x + threadIdx.x;
  int stride = gridDim.x * blockDim.x;
  for (int t = i; t < N_NODES; t += stride) cnt[t] = 0;
  for (int t = i; t < N_GRAPHS * HID; t += stride) pooled[t] = 0.f;
  for (int t = i; t < N_GRAPHS; t += stride) gcnt[t] = 0.f;
}

// ---------------- degree count (in-edges per dst) ----------------
__global__ void k_edge_count(const int* __restrict__ ei, int* __restrict__ cnt) {
  int e = blockIdx.x * blockDim.x + threadIdx.x;
  if (e < N_EDGES) atomicAdd(&cnt[ei[N_EDGES + e]], 1);
}

// ---------------- hierarchical exclusive scan ----------------
__global__ void k_scan1(const int* __restrict__ cnt, int* __restrict__ row_ptr,
                        int* __restrict__ chunk_sums) {
  __shared__ int s[CHUNK];
  int t = threadIdx.x;
  int gid = blockIdx.x * CHUNK + t;
  int v = (gid < N_NODES) ? cnt[gid] : 0;
  s[t] = v;
  __syncthreads();
  for (int off = 1; off < CHUNK; off <<= 1) {
    int add = (t >= off) ? s[t - off] : 0;
    __syncthreads();
    s[t] += add;
    __syncthreads();
  }
  if (gid < N_NODES) row_ptr[gid] = s[t] - v;     // chunk-local exclusive
  if (t == CHUNK - 1) chunk_sums[blockIdx.x] = s[t];
}

__global__ void k_scan2(const int* __restrict__ chunk_sums, int* __restrict__ chunk_off) {
  __shared__ int s[128];
  int t = threadIdx.x;
  int v = (t < NCHUNK) ? chunk_sums[t] : 0;
  s[t] = v;
  __syncthreads();
  for (int off = 1; off < 128; off <<= 1) {
    int add = (t >= off) ? s[t - off] : 0;
    __syncthreads();
    s[t] += add;
    __syncthreads();
  }
  if (t < NCHUNK) chunk_off[t] = s[t] - v;        // exclusive
}

__global__ void k_scan3(int* __restrict__ row_ptr, const int* __restrict__ chunk_off,
                        int* __restrict__ cursor) {
  int i = blockIdx.x * blockDim.x + threadIdx.x;
  if (i < N_NODES) {
    int v = row_ptr[i] + chunk_off[i / CHUNK];
    row_ptr[i] = v;
    cursor[i] = v;
  }
  if (i == 0) row_ptr[N_NODES] = N_EDGES;
}

__global__ void k_dinv(const int* __restrict__ cnt, float* __restrict__ dinv) {
  int i = blockIdx.x * blockDim.x + threadIdx.x;
  if (i < N_NODES) dinv[i] = rsqrtf((float)cnt[i] + 1.0f);  // +1 self-loop, deg>=1
}

// ---------------- CSR fill (sorted-by-dst adjacency + edge norms) ----------------
__global__ void k_csr_fill(const int* __restrict__ ei, const float* __restrict__ dinv,
                           int* __restrict__ cursor, int* __restrict__ col,
                           float* __restrict__ wn) {
  int e = blockIdx.x * blockDim.x + threadIdx.x;
  if (e < N_EDGES) {
    int s = ei[e];
    int d = ei[N_EDGES + e];
    int p = atomicAdd(&cursor[d], 1);
    col[p] = s;
    wn[p] = dinv[s] * dinv[d];
  }
}

// ---------------- fp32 GEMM: T[M,128] = H[M,128] @ W[128,128] ----------------
#define BM 64
#define BK 16
__global__ __launch_bounds__(256) void k_gemm(const float* __restrict__ H,
                                              const float* __restrict__ W,
                                              float* __restrict__ T) {
  __shared__ float hs[BM][BK + 1];
  __shared__ float ws[BK][HID];
  int tid = threadIdx.x;
  int tx = tid & 31;   // cols 4*tx .. 4*tx+3
  int ty = tid >> 5;   // rows ty*8 .. ty*8+7
  int m0 = blockIdx.x * BM;
  float acc[8][4] = {};

  for (int kc = 0; kc < HID; kc += BK) {
    #pragma unroll
    for (int j = 0; j < 4; ++j) {               // A tile: 64x16
      int id = tid + 256 * j;
      int i = id >> 4, kk = id & 15;
      int row = m0 + i;
      hs[i][kk] = (row < N_NODES) ? H[row * HID + kc + kk] : 0.f;
    }
    #pragma unroll
    for (int j = 0; j < 8; ++j) {               // B tile: 16x128
      int id = tid + 256 * j;
      int kk = id >> 7, c = id & 127;
      ws[kk][c] = W[(kc + kk) * HID + c];
    }
    __syncthreads();
    #pragma unroll
    for (int kk = 0; kk < BK; ++kk) {
      float4 b = *(const float4*)&ws[kk][tx * 4];
      #pragma unroll
      for (int i = 0; i < 8; ++i) {
        float a = hs[ty * 8 + i][kk];
        acc[i][0] += a * b.x; acc[i][1] += a * b.y;
        acc[i][2] += a * b.z; acc[i][3] += a * b.w;
      }
    }
    __syncthreads();
  }
  #pragma unroll
  for (int i = 0; i < 8; ++i) {
    int row = m0 + ty * 8 + i;
    if (row < N_NODES) {
      float4 o = {acc[i][0], acc[i][1], acc[i][2], acc[i][3]};
      *(float4*)&T[row * HID + tx * 4] = o;
    }
  }
}

// ---------------- aggregation: one wave per node, lane = 2 channels ----------------
__global__ __launch_bounds__(256) void k_agg(const float* __restrict__ T,
                                             const int* __restrict__ row_ptr,
                                             const int* __restrict__ col,
                                             const float* __restrict__ wn,
                                             const float* __restrict__ dinv,
                                             const float* __restrict__ bias,
                                             float* __restrict__ Hout) {
  int wid = (blockIdx.x * blockDim.x + threadIdx.x) >> 6;  // node id
  int lane = threadIdx.x & 63;
  if (wid >= N_NODES) return;
  const float2* T2 = (const float2*)T;
  float dn = dinv[wid];
  float2 t = T2[wid * 64 + lane];
  float2 acc;
  acc.x = dn * dn * t.x;                    // self-loop term
  acc.y = dn * dn * t.y;
  int p0 = row_ptr[wid], p1 = row_ptr[wid + 1];
  for (int p = p0; p < p1; ++p) {
    int s = col[p];
    float w = wn[p];
    float2 v = T2[s * 64 + lane];
    acc.x += w * v.x;
    acc.y += w * v.y;
  }
  float2 b = ((const float2*)bias)[lane];
  float2 o;
  o.x = fmaxf(acc.x + b.x, 0.f);
  o.y = fmaxf(acc.y + b.y, 0.f);
  ((float2*)Hout)[wid * 64 + lane] = o;
}

// ---------------- mean pool (batch is sorted -> run-length flush) ----------------
#define NODES_PER_BLOCK 256
__global__ __launch_bounds__(128) void k_pool(const float* __restrict__ H,
                                              const int* __restrict__ batch,
                                              float* __restrict__ pooled,
                                              float* __restrict__ gcnt) {
  int c = threadIdx.x;                       // channel 0..127
  int n0 = blockIdx.x * NODES_PER_BLOCK;
  if (n0 >= N_NODES) return;
  int n1 = min(n0 + NODES_PER_BLOCK, N_NODES);
  float sum = 0.f;
  float cntr = 0.f;
  int cur = batch[n0];
  for (int n = n0; n < n1; ++n) {
    int g = batch[n];
    if (g != cur) {
      atomicAdd(&pooled[cur * HID + c], sum);
      if (c == 0) atomicAdd(&gcnt[cur], cntr);
      sum = 0.f; cntr = 0.f; cur = g;
    }
    sum += H[n * HID + c];
    cntr += 1.f;
  }
  atomicAdd(&pooled[cur * HID + c], sum);
  if (c == 0) atomicAdd(&gcnt[cur], cntr);
}

// ---------------- output: out[g,c] = (pooled[g]/cnt) @ w_out + b_out ----------------
__global__ __launch_bounds__(64) void k_out(const float* __restrict__ pooled,
                                            const float* __restrict__ gcnt,
                                            const float* __restrict__ w_out,
                                            const float* __restrict__ b_out,
                                            float* __restrict__ out) {
  int g = blockIdx.x;    // 0..255
  int c = threadIdx.x;   // 0..63
  __shared__ float p[HID];
  float inv = 1.0f / fmaxf(gcnt[g], 1.0f);
  for (int k = c; k < HID; k += 64) p[k] = pooled[g * HID + k] * inv;
  __syncthreads();
  float acc = b_out[c];
  #pragma unroll 8
  for (int k = 0; k < HID; ++k) acc += p[k] * w_out[k * OUT_CH + c];
  out[g * OUT_CH + c] = acc;
}

extern "C" void kernel_launch(void* const* d_in, const int* in_sizes, int n_in,
                              void* d_out, int out_size, void* d_ws, size_t ws_size,
                              hipStream_t stream) {
  const float* x     = (const float*)d_in[0];
  const int*   ei    = (const int*)d_in[1];
  const int*   batch = (const int*)d_in[2];
  const float* w1    = (const float*)d_in[3];
  const float* b1    = (const float*)d_in[4];
  const float* w2    = (const float*)d_in[5];
  const float* b2    = (const float*)d_in[6];
  const float* w3    = (const float*)d_in[7];
  const float* b3    = (const float*)d_in[8];
  const float* w_out = (const float*)d_in[9];
  const float* b_out = (const float*)d_in[10];
  float* out = (float*)d_out;

  // workspace carve-up
  char* w = (char*)d_ws;
  auto alloc = [&](size_t bytes) { void* p = (void*)w; w += (bytes + 255) & ~(size_t)255; return p; };
  int*   cnt        = (int*)  alloc((size_t)N_NODES * 4);
  int*   row_ptr    = (int*)  alloc((size_t)(N_NODES + 1) * 4);
  int*   cursor     = (int*)  alloc((size_t)N_NODES * 4);
  float* dinv       = (float*)alloc((size_t)N_NODES * 4);
  int*   chunk_sums = (int*)  alloc((size_t)NCHUNK * 4);
  int*   chunk_off  = (int*)  alloc((size_t)NCHUNK * 4);
  int*   col        = (int*)  alloc((size_t)N_EDGES * 4);
  float* wn         = (float*)alloc((size_t)N_EDGES * 4);
  float* H0         = (float*)alloc((size_t)N_NODES * HID * 4);
  float* H1         = (float*)alloc((size_t)N_NODES * HID * 4);
  float* pooled     = (float*)alloc((size_t)N_GRAPHS * HID * 4);
  float* gcnt       = (float*)alloc((size_t)N_GRAPHS * 4);

  const int EB = (N_EDGES + 255) / 256;        // 6250
  const int NB = (N_NODES + 255) / 256;        // 391
  const int GB = (N_NODES + BM - 1) / BM;      // 1563
  const int AB = (N_NODES + 3) / 4;            // 25000 (4 waves/block)
  const int PB = (N_NODES + NODES_PER_BLOCK - 1) / NODES_PER_BLOCK;  // 391

  k_init<<<256, 256, 0, stream>>>(cnt, pooled, gcnt);
  k_edge_count<<<EB, 256, 0, stream>>>(ei, cnt);
  k_scan1<<<NCHUNK, CHUNK, 0, stream>>>(cnt, row_ptr, chunk_sums);
  k_scan2<<<1, 128, 0, stream>>>(chunk_sums, chunk_off);
  k_scan3<<<NB, 256, 0, stream>>>(row_ptr, chunk_off, cursor);
  k_dinv<<<NB, 256, 0, stream>>>(cnt, dinv);
  k_csr_fill<<<EB, 256, 0, stream>>>(ei, dinv, cursor, col, wn);

  // layer 1
  k_gemm<<<GB, 256, 0, stream>>>(x, w1, H1);
  k_agg<<<AB, 256, 0, stream>>>(H1, row_ptr, col, wn, dinv, b1, H0);
  // layer 2
  k_gemm<<<GB, 256, 0, stream>>>(H0, w2, H1);
  k_agg<<<AB, 256, 0, stream>>>(H1, row_ptr, col, wn, dinv, b2, H0);
  // layer 3
  k_gemm<<<GB, 256, 0, stream>>>(H0, w3, H1);
  k_agg<<<AB, 256, 0, stream>>>(H1, row_ptr, col, wn, dinv, b3, H0);

  k_pool<<<PB, 128, 0, stream>>>(H0, batch, pooled, gcnt);
  k_out<<<N_GRAPHS, 64, 0, stream>>>(pooled, gcnt, w_out, b_out, out);
}

// Round 2
// 589.903 us; speedup vs baseline: 1.6643x; 1.6643x over previous
//
#include <hip/hip_runtime.h>
#include <hip/hip_fp16.h>

#define N_NODES 100000
#define N_EDGES 1600000
#define HID 128
#define OUT_CH 64
#define N_GRAPHS 256
#define CHUNK 1024
#define NCHUNK ((N_NODES + CHUNK - 1) / CHUNK)   // 98

// ---------------- init ----------------
__global__ void k_init(int* cnt, float* pooled, float* gcnt) {
  int i = blockIdx.x * blockDim.x + threadIdx.x;
  int stride = gridDim.x * blockDim.x;
  for (int t = i; t < N_NODES; t += stride) cnt[t] = 0;
  for (int t = i; t < N_GRAPHS * HID; t += stride) pooled[t] = 0.f;
  for (int t = i; t < N_GRAPHS; t += stride) gcnt[t] = 0.f;
}

// ---------------- degree count (in-edges per dst) ----------------
__global__ void k_edge_count(const int* __restrict__ ei, int* __restrict__ cnt) {
  int e = blockIdx.x * blockDim.x + threadIdx.x;
  if (e < N_EDGES) atomicAdd(&cnt[ei[N_EDGES + e]], 1);
}

// ---------------- hierarchical exclusive scan ----------------
__global__ void k_scan1(const int* __restrict__ cnt, int* __restrict__ row_ptr,
                        int* __restrict__ chunk_sums) {
  __shared__ int s[CHUNK];
  int t = threadIdx.x;
  int gid = blockIdx.x * CHUNK + t;
  int v = (gid < N_NODES) ? cnt[gid] : 0;
  s[t] = v;
  __syncthreads();
  for (int off = 1; off < CHUNK; off <<= 1) {
    int add = (t >= off) ? s[t - off] : 0;
    __syncthreads();
    s[t] += add;
    __syncthreads();
  }
  if (gid < N_NODES) row_ptr[gid] = s[t] - v;     // chunk-local exclusive
  if (t == CHUNK - 1) chunk_sums[blockIdx.x] = s[t];
}

__global__ void k_scan2(const int* __restrict__ chunk_sums, int* __restrict__ chunk_off) {
  __shared__ int s[128];
  int t = threadIdx.x;
  int v = (t < NCHUNK) ? chunk_sums[t] : 0;
  s[t] = v;
  __syncthreads();
  for (int off = 1; off < 128; off <<= 1) {
    int add = (t >= off) ? s[t - off] : 0;
    __syncthreads();
    s[t] += add;
    __syncthreads();
  }
  if (t < NCHUNK) chunk_off[t] = s[t] - v;        // exclusive
}

__global__ void k_scan3(int* __restrict__ row_ptr, const int* __restrict__ chunk_off,
                        int* __restrict__ cursor) {
  int i = blockIdx.x * blockDim.x + threadIdx.x;
  if (i < N_NODES) {
    int v = row_ptr[i] + chunk_off[i / CHUNK];
    row_ptr[i] = v;
    cursor[i] = v;
  }
  if (i == 0) row_ptr[N_NODES] = N_EDGES;
}

__global__ void k_dinv(const int* __restrict__ cnt, float* __restrict__ dinv) {
  int i = blockIdx.x * blockDim.x + threadIdx.x;
  if (i < N_NODES) dinv[i] = rsqrtf((float)cnt[i] + 1.0f);  // +1 self-loop, deg>=1
}

// ---------------- CSR fill: E[p] = {src, bits(norm)} sorted by dst ----------------
__global__ void k_csr_fill(const int* __restrict__ ei, const float* __restrict__ dinv,
                           int* __restrict__ cursor, int2* __restrict__ E) {
  int e = blockIdx.x * blockDim.x + threadIdx.x;
  if (e < N_EDGES) {
    int s = ei[e];
    int d = ei[N_EDGES + e];
    int p = atomicAdd(&cursor[d], 1);
    E[p] = make_int2(s, __float_as_int(dinv[s] * dinv[d]));
  }
}

// ---------------- fp32 GEMM: T[M,128] = H[M,128] @ W[128,128], fp16 out ----------------
#define BM 64
#define BK 16
__global__ __launch_bounds__(256) void k_gemm(const float* __restrict__ H,
                                              const float* __restrict__ W,
                                              __half* __restrict__ T) {
  __shared__ float hs[BM][BK + 1];
  __shared__ float ws[BK][HID];
  int tid = threadIdx.x;
  int tx = tid & 31;   // cols 4*tx .. 4*tx+3
  int ty = tid >> 5;   // rows ty*8 .. ty*8+7
  int m0 = blockIdx.x * BM;
  float acc[8][4] = {};

  for (int kc = 0; kc < HID; kc += BK) {
    #pragma unroll
    for (int j = 0; j < 4; ++j) {               // A tile: 64x16
      int id = tid + 256 * j;
      int i = id >> 4, kk = id & 15;
      int row = m0 + i;
      hs[i][kk] = (row < N_NODES) ? H[(size_t)row * HID + kc + kk] : 0.f;
    }
    #pragma unroll
    for (int j = 0; j < 8; ++j) {               // B tile: 16x128
      int id = tid + 256 * j;
      int kk = id >> 7, c = id & 127;
      ws[kk][c] = W[(size_t)(kc + kk) * HID + c];
    }
    __syncthreads();
    #pragma unroll
    for (int kk = 0; kk < BK; ++kk) {
      float4 b = *(const float4*)&ws[kk][tx * 4];
      #pragma unroll
      for (int i = 0; i < 8; ++i) {
        float a = hs[ty * 8 + i][kk];
        acc[i][0] += a * b.x; acc[i][1] += a * b.y;
        acc[i][2] += a * b.z; acc[i][3] += a * b.w;
      }
    }
    __syncthreads();
  }
  #pragma unroll
  for (int i = 0; i < 8; ++i) {
    int row = m0 + ty * 8 + i;
    if (row < N_NODES) {
      __half2 h01 = __floats2half2_rn(acc[i][0], acc[i][1]);
      __half2 h23 = __floats2half2_rn(acc[i][2], acc[i][3]);
      uint2 o;
      o.x = *(unsigned int*)&h01;
      o.y = *(unsigned int*)&h23;
      *(uint2*)&T[(size_t)row * HID + tx * 4] = o;
    }
  }
}

// ---------------- aggregation: wave/node, lane=2ch, unroll-4 gathers ----------------
__global__ __launch_bounds__(256) void k_agg(const __half* __restrict__ T,
                                             const int* __restrict__ row_ptr,
                                             const int2* __restrict__ E,
                                             const float* __restrict__ dinv,
                                             const float* __restrict__ bias,
                                             float* __restrict__ Hout) {
  int wid = (blockIdx.x * blockDim.x + threadIdx.x) >> 6;  // node id
  int lane = threadIdx.x & 63;
  if (wid >= N_NODES) return;
  const __half2* T2 = (const __half2*)T;
  float dn = dinv[wid];
  float2 t = __half22float2(T2[(size_t)wid * 64 + lane]);
  float ax = dn * dn * t.x;                    // self-loop term
  float ay = dn * dn * t.y;
  int p = row_ptr[wid], p1 = row_ptr[wid + 1];
  for (; p + 4 <= p1; p += 4) {
    int2 e0 = E[p], e1 = E[p + 1], e2 = E[p + 2], e3 = E[p + 3];
    __half2 v0 = T2[(size_t)e0.x * 64 + lane];
    __half2 v1 = T2[(size_t)e1.x * 64 + lane];
    __half2 v2 = T2[(size_t)e2.x * 64 + lane];
    __half2 v3 = T2[(size_t)e3.x * 64 + lane];
    float w0 = __int_as_float(e0.y), w1 = __int_as_float(e1.y);
    float w2 = __int_as_float(e2.y), w3 = __int_as_float(e3.y);
    float2 f0 = __half22float2(v0), f1 = __half22float2(v1);
    float2 f2 = __half22float2(v2), f3 = __half22float2(v3);
    ax += w0 * f0.x; ay += w0 * f0.y;
    ax += w1 * f1.x; ay += w1 * f1.y;
    ax += w2 * f2.x; ay += w2 * f2.y;
    ax += w3 * f3.x; ay += w3 * f3.y;
  }
  for (; p < p1; ++p) {
    int2 e = E[p];
    float2 f = __half22float2(T2[(size_t)e.x * 64 + lane]);
    float w = __int_as_float(e.y);
    ax += w * f.x; ay += w * f.y;
  }
  float2 b = ((const float2*)bias)[lane];
  float2 o;
  o.x = fmaxf(ax + b.x, 0.f);
  o.y = fmaxf(ay + b.y, 0.f);
  ((float2*)Hout)[(size_t)wid * 64 + lane] = o;
}

// ---------------- mean pool (batch is sorted -> run-length flush) ----------------
#define NODES_PER_BLOCK 64
__global__ __launch_bounds__(128) void k_pool(const float* __restrict__ H,
                                              const int* __restrict__ batch,
                                              float* __restrict__ pooled,
                                              float* __restrict__ gcnt) {
  int c = threadIdx.x;                       // channel 0..127
  int n0 = blockIdx.x * NODES_PER_BLOCK;
  if (n0 >= N_NODES) return;
  int n1 = min(n0 + NODES_PER_BLOCK, N_NODES);
  float sum = 0.f;
  float cntr = 0.f;
  int cur = batch[n0];
  for (int n = n0; n < n1; ++n) {
    int g = batch[n];
    if (g != cur) {
      atomicAdd(&pooled[cur * HID + c], sum);
      if (c == 0) atomicAdd(&gcnt[cur], cntr);
      sum = 0.f; cntr = 0.f; cur = g;
    }
    sum += H[(size_t)n * HID + c];
    cntr += 1.f;
  }
  atomicAdd(&pooled[cur * HID + c], sum);
  if (c == 0) atomicAdd(&gcnt[cur], cntr);
}

// ---------------- output: out[g,c] = (pooled[g]/cnt) @ w_out + b_out ----------------
__global__ __launch_bounds__(64) void k_out(const float* __restrict__ pooled,
                                            const float* __restrict__ gcnt,
                                            const float* __restrict__ w_out,
                                            const float* __restrict__ b_out,
                                            float* __restrict__ out) {
  int g = blockIdx.x;    // 0..255
  int c = threadIdx.x;   // 0..63
  __shared__ float p[HID];
  float inv = 1.0f / fmaxf(gcnt[g], 1.0f);
  for (int k = c; k < HID; k += 64) p[k] = pooled[g * HID + k] * inv;
  __syncthreads();
  float acc = b_out[c];
  #pragma unroll 8
  for (int k = 0; k < HID; ++k) acc += p[k] * w_out[k * OUT_CH + c];
  out[g * OUT_CH + c] = acc;
}

extern "C" void kernel_launch(void* const* d_in, const int* in_sizes, int n_in,
                              void* d_out, int out_size, void* d_ws, size_t ws_size,
                              hipStream_t stream) {
  const float* x     = (const float*)d_in[0];
  const int*   ei    = (const int*)d_in[1];
  const int*   batch = (const int*)d_in[2];
  const float* w1    = (const float*)d_in[3];
  const float* b1    = (const float*)d_in[4];
  const float* w2    = (const float*)d_in[5];
  const float* b2    = (const float*)d_in[6];
  const float* w3    = (const float*)d_in[7];
  const float* b3    = (const float*)d_in[8];
  const float* w_out = (const float*)d_in[9];
  const float* b_out = (const float*)d_in[10];
  float* out = (float*)d_out;

  // workspace carve-up
  char* w = (char*)d_ws;
  auto alloc = [&](size_t bytes) { void* p = (void*)w; w += (bytes + 255) & ~(size_t)255; return p; };
  int*   cnt        = (int*)  alloc((size_t)N_NODES * 4);
  int*   row_ptr    = (int*)  alloc((size_t)(N_NODES + 1) * 4);
  int*   cursor     = (int*)  alloc((size_t)N_NODES * 4);
  float* dinv       = (float*)alloc((size_t)N_NODES * 4);
  int*   chunk_sums = (int*)  alloc((size_t)NCHUNK * 4);
  int*   chunk_off  = (int*)  alloc((size_t)NCHUNK * 4);
  int2*  E          = (int2*) alloc((size_t)N_EDGES * 8);
  __half* T         = (__half*)alloc((size_t)N_NODES * HID * 2);
  float* H0         = (float*)alloc((size_t)N_NODES * HID * 4);
  float* pooled     = (float*)alloc((size_t)N_GRAPHS * HID * 4);
  float* gcnt       = (float*)alloc((size_t)N_GRAPHS * 4);

  const int EB = (N_EDGES + 255) / 256;        // 6250
  const int NB = (N_NODES + 255) / 256;        // 391
  const int GB = (N_NODES + BM - 1) / BM;      // 1563
  const int AB = (N_NODES + 3) / 4;            // 25000 (4 waves/block)
  const int PB = (N_NODES + NODES_PER_BLOCK - 1) / NODES_PER_BLOCK;  // 1563

  k_init<<<256, 256, 0, stream>>>(cnt, pooled, gcnt);
  k_edge_count<<<EB, 256, 0, stream>>>(ei, cnt);
  k_scan1<<<NCHUNK, CHUNK, 0, stream>>>(cnt, row_ptr, chunk_sums);
  k_scan2<<<1, 128, 0, stream>>>(chunk_sums, chunk_off);
  k_scan3<<<NB, 256, 0, stream>>>(row_ptr, chunk_off, cursor);
  k_dinv<<<NB, 256, 0, stream>>>(cnt, dinv);
  k_csr_fill<<<EB, 256, 0, stream>>>(ei, dinv, cursor, E);

  // layer 1
  k_gemm<<<GB, 256, 0, stream>>>(x, w1, T);
  k_agg<<<AB, 256, 0, stream>>>(T, row_ptr, E, dinv, b1, H0);
  // layer 2
  k_gemm<<<GB, 256, 0, stream>>>(H0, w2, T);
  k_agg<<<AB, 256, 0, stream>>>(T, row_ptr, E, dinv, b2, H0);
  // layer 3
  k_gemm<<<GB, 256, 0, stream>>>(H0, w3, T);
  k_agg<<<AB, 256, 0, stream>>>(T, row_ptr, E, dinv, b3, H0);

  k_pool<<<PB, 128, 0, stream>>>(H0, batch, pooled, gcnt);
  k_out<<<N_GRAPHS, 64, 0, stream>>>(pooled, gcnt, w_out, b_out, out);
}